// Round 11
// baseline (109.475 us; speedup 1.0000x reference)
//
#include <hip/hip_runtime.h>
#include <hip/hip_bf16.h>

typedef __attribute__((ext_vector_type(8))) short short8;
typedef __attribute__((ext_vector_type(4))) float float4v;
typedef __attribute__((ext_vector_type(16))) float float16v;

// Workspace layout (bytes):
//   xTg  bf16 [16 b][32 g][34 h][34 w][8 c]             : 9,469,952
//   Wg   bf16 [9 s][4 pair][4 nq][8 g][64 n][8 c]       : 1,179,648
//   biasout f32 [256]                                   : 1,024
#define XT_BYTES (16*32*34*34*8*2)
#define WG_BYTES (9*4*4*8*64*8*2)

// ---------------------------------------------------------------------------
// k_prep: fused producer. (unchanged from R12)
// ---------------------------------------------------------------------------
__global__ __launch_bounds__(256) void k_prep(const float* __restrict__ x,
                                              const float* __restrict__ tw1,
                                              const float* __restrict__ tw2,
                                              const float* __restrict__ bias,
                                              __hip_bfloat16* __restrict__ xTg,
                                              __hip_bfloat16* __restrict__ Wg,
                                              float* __restrict__ biasout) {
  __shared__ __align__(16) char smem[256 * 33 * 4];   // 33792 B, both phases fit
  int blk = blockIdx.x;
  int tid = threadIdx.x;

  if (blk < 512) {   // ---------------- transpose ----------------
    float* tile = (float*)smem;
    char* xTB = (char*)xTg;
    int h = blk & 31, b = blk >> 5;
    {
      int w4 = (tid & 7) * 4, c0 = tid >> 3;
#pragma unroll
      for (int j = 0; j < 8; ++j) {
        int ci = c0 + 32 * j;
        float4 v = *(const float4*)&x[((b * 256 + ci) * 32 + h) * 32 + w4];
        *(float4*)&tile[ci * 33 + w4] = v;
      }
    }
    __syncthreads();
    {
      int g0 = tid >> 5, w = tid & 31;
#pragma unroll
      for (int gi = 0; gi < 4; ++gi) {
        int g = gi * 8 + g0;
        union { short8 s; __hip_bfloat16 hv[8]; } pk;
#pragma unroll
        for (int cc = 0; cc < 8; ++cc)
          pk.hv[cc] = __float2bfloat16(tile[(g * 8 + cc) * 33 + w]);
        *(short8*)(xTB + ((((b * 32 + g) * 34 + h + 1) * 34) + (w + 1)) * 16) = pk.s;
      }
    }
    if (h < 2) {  // h==0 -> row 0 + col 0 ; h==1 -> row 33 + col 33 (all g)
      uint4 z4 = {0u, 0u, 0u, 0u};
      int edge = h * 33;
      for (int i = tid; i < 32 * 34; i += 256) {
        int g = i / 34, w = i - g * 34;
        *(uint4*)(xTB + ((((b * 32 + g) * 34 + edge) * 34) + w) * 16) = z4;
      }
      for (int i = tid; i < 32 * 32; i += 256) {
        int g = i >> 5, hh = 1 + (i & 31);
        *(uint4*)(xTB + ((((b * 32 + g) * 34 + hh) * 34) + edge) * 16) = z4;
      }
    }
    return;
  }

  // ---------------- build_w ----------------
  int wblk = blk - 512;
  if (wblk == 144) {
    if (tid < 256) {
      float a = 0.f;
#pragma unroll
      for (int s = 0; s < 9; ++s) a += bias[s * 256 + tid];
      biasout[tid] = a * (1.f / 9.f);
    }
    return;
  }
  float* mat = (float*)smem;              // 256*17*4 = 17408 B
  float* tws = (float*)(smem + 17408);    // 2*255*4*4 = 8160 B
  int sidx = wblk >> 4;
  int colbase = (wblk & 15) * 16;

  for (int i = tid; i < 255 * 4; i += 256) {
    tws[i]           = tw1[sidx * 255 * 4 + i];
    tws[255 * 4 + i] = tw2[sidx * 255 * 4 + i];
  }
  {
    int r = tid;
#pragma unroll
    for (int c = 0; c < 16; ++c) mat[r * 17 + c] = (r == colbase + c) ? 1.f : 0.f;
  }

  int c  = tid & 15;
  int pg = tid >> 4;
  for (int ph = 0; ph < 2; ++ph) {
    for (int si = 0; si < 8; ++si) {
      int lg = ph ? si : (7 - si);
      int st = 1 << lg;
      __syncthreads();
      float x0[8], x1[8], t0[8], t1[8], t2[8], t3[8];
#pragma unroll
      for (int i = 0; i < 8; ++i) {
        int qp = pg * 8 + i;
        int li = qp & (st - 1);
        int gi = qp >> lg;
        int p0 = (gi << (lg + 1)) | li;
        int p1 = p0 + st;
        float4 tv = *(const float4*)&tws[(ph * 255 + st - 1 + li) * 4];
        t0[i] = tv.x; t1[i] = tv.y; t2[i] = tv.z; t3[i] = tv.w;
        x0[i] = mat[p0 * 17 + c];
        x1[i] = mat[p1 * 17 + c];
      }
#pragma unroll
      for (int i = 0; i < 8; ++i) {
        int qp = pg * 8 + i;
        int li = qp & (st - 1);
        int gi = qp >> lg;
        int p0 = (gi << (lg + 1)) | li;
        int p1 = p0 + st;
        mat[p0 * 17 + c] = t0[i] * x0[i] + t1[i] * x1[i];
        mat[p1 * 17 + c] = t2[i] * x0[i] + t3[i] * x1[i];
      }
    }
  }
  __syncthreads();

  for (int idx = tid; idx < 256 * 16; idx += 256) {
    int r = idx >> 4, cc = idx & 15;
    int cg = colbase + cc;
    int pr = cg >> 6, g = (cg >> 3) & 7, c8 = cg & 7;
    int nq = r >> 6, nl = r & 63;
    int o = ((((sidx * 4 + pr) * 4 + nq) * 8 + g) * 64 + nl) * 8 + c8;
    Wg[o] = __float2bfloat16(mat[r * 17 + cc] * (1.f / 9.f));
  }
}

// ---------------------------------------------------------------------------
// k_gemm R23 = R22 (depth-6 register pipeline) with the asm made
// allocation-safe. R22 core-dumped: "=v" (no early-clobber) let the allocator
// overlap async load destinations with the address pair -> load-1 writeback
// corrupted the address before loads 2-4 issued -> page fault. Fix: "=&v"
// early-clobber on every destination + split A/B into separate asm blocks.
// Theory unchanged (R19 counters + R21 occupancy-null + R19 warm-rep null =>
// per-wave serial chain ~1060 cyc/body): 6-deep pinned-issue pipeline,
// counted vmcnt(20) steady / 20,16,12,8,4,0 tail, sched_barrier after every
// waitcnt (rule #18). Body order p-major, S=si*3+sj ascending -- accumulation
// order bit-identical to R21. ~190 VGPR, no spills -> vmcnt discipline sound.
// Shape/grid/epilogue = R21 (acc[2][2], grid 1024, XCD swizzle).
// ---------------------------------------------------------------------------

#define ISSUE(SL, P, S, SI, SJ)                                               \
  { const char* ap_ = pA + (P)*32768 + (S)*131072;                            \
    const char* bp_ = pB + (P)*147968 + (SI)*544 + (SJ)*16;                   \
    asm volatile("global_load_dwordx4 %0, %2, off\n\t"                        \
                 "global_load_dwordx4 %1, %2, off offset:512"                 \
      : "=&v"(ra[SL][0]), "=&v"(ra[SL][1]) : "v"(ap_));                       \
    asm volatile("global_load_dwordx4 %0, %2, off\n\t"                        \
                 "global_load_dwordx4 %1, %2, off offset:544"                 \
      : "=&v"(rb[SL][0]), "=&v"(rb[SL][1]) : "v"(bp_)); }

#define WAITB_(N) asm volatile("s_waitcnt vmcnt(" #N ")" ::: "memory")
#define WAITB(N) WAITB_(N); __builtin_amdgcn_sched_barrier(0)

#define MM4(SL)                                                               \
  acc[0][0] = __builtin_amdgcn_mfma_f32_32x32x16_bf16(ra[SL][0], rb[SL][0], acc[0][0], 0, 0, 0); \
  acc[0][1] = __builtin_amdgcn_mfma_f32_32x32x16_bf16(ra[SL][0], rb[SL][1], acc[0][1], 0, 0, 0); \
  acc[1][0] = __builtin_amdgcn_mfma_f32_32x32x16_bf16(ra[SL][1], rb[SL][0], acc[1][0], 0, 0, 0); \
  acc[1][1] = __builtin_amdgcn_mfma_f32_32x32x16_bf16(ra[SL][1], rb[SL][1], acc[1][1], 0, 0, 0);

#define BODY(SL, JP, JS, JSI, JSJ) { WAITB(20); MM4(SL); ISSUE(SL, JP, JS, JSI, JSJ); }
#define BODYT(SL, N)               { WAITB(N);  MM4(SL); }

__global__ __launch_bounds__(256, 2) void k_gemm(const __hip_bfloat16* __restrict__ xTg,
                                                 const __hip_bfloat16* __restrict__ Wg,
                                                 const float* __restrict__ biasout,
                                                 float* __restrict__ out) {
  __shared__ __align__(64) char lds[16384];
  const char* WgB = (const char*)Wg;
  const char* xTB = (const char*)xTg;

  // XCD swizzle: xcd = blk&7 owns b in {2*xcd, 2*xcd+1}. Grid 1024.
  int blk  = blockIdx.x;
  int rest = blk >> 3;              // 0..127
  int b    = 2 * (blk & 7) + (rest >> 6);
  int r2   = rest & 63;
  int nq   = r2 & 3;
  int pt   = r2 >> 2;               // 0..15
  int h0   = pt * 2;                // output rows h0, h0+1

  int tid  = threadIdx.x;
  int lane = tid & 63;
  int wk   = tid >> 6;              // wave = k-quarter 0..3
  int half = lane >> 5;
  int l31  = lane & 31;

  float16v acc[2][2];               // [mt][p2] -- 64 regs
#pragma unroll
  for (int mt = 0; mt < 2; ++mt)
#pragma unroll
    for (int p2 = 0; p2 < 2; ++p2)
#pragma unroll
      for (int e = 0; e < 16; ++e) acc[mt][p2][e] = 0.f;

  // Per-lane bases (addressing identical to R21's direct loads):
  // A body addr = pA + P*32768 + S*131072 (+512 for rows 32..63)
  int aoff = ((2 * wk + half) * 64 + l31) * 16;
  const char* pA = WgB + nq * 8192 + aoff;
  // B body addr = pB + P*147968 + SI*544 + SJ*16 (+544 for row h0+1)
  int bbase = ((((b * 32 + 2 * wk + half) * 34 + h0) * 34) + l31) * 16;
  const char* pB = xTB + bbase;

  short8 ra[6][2];                  // A pipeline slots (a0, a1)
  short8 rb[6][2];                  // B pipeline slots (rows h0, h0+1)

  // Prologue: issue bodies 0..5 (24 loads in flight).
  ISSUE(0, 0,0,0,0) ISSUE(1, 0,1,0,1) ISSUE(2, 0,2,0,2)
  ISSUE(3, 0,3,1,0) ISSUE(4, 0,4,1,1) ISSUE(5, 0,5,1,2)

  // Bodies 0..29: wait body i (vmcnt 20), 4 MFMAs, issue body i+6.
  BODY(0, 0,6,2,0) BODY(1, 0,7,2,1) BODY(2, 0,8,2,2)
  BODY(3, 1,0,0,0) BODY(4, 1,1,0,1) BODY(5, 1,2,0,2)
  BODY(0, 1,3,1,0) BODY(1, 1,4,1,1) BODY(2, 1,5,1,2)
  BODY(3, 1,6,2,0) BODY(4, 1,7,2,1) BODY(5, 1,8,2,2)
  BODY(0, 2,0,0,0) BODY(1, 2,1,0,1) BODY(2, 2,2,0,2)
  BODY(3, 2,3,1,0) BODY(4, 2,4,1,1) BODY(5, 2,5,1,2)
  BODY(0, 2,6,2,0) BODY(1, 2,7,2,1) BODY(2, 2,8,2,2)
  BODY(3, 3,0,0,0) BODY(4, 3,1,0,1) BODY(5, 3,2,0,2)
  BODY(0, 3,3,1,0) BODY(1, 3,4,1,1) BODY(2, 3,5,1,2)
  BODY(3, 3,6,2,0) BODY(4, 3,7,2,1) BODY(5, 3,8,2,2)
  // Tail bodies 30..35: drain 20,16,12,8,4,0.
  BODYT(0, 20) BODYT(1, 16) BODYT(2, 12) BODYT(3, 8) BODYT(4, 4) BODYT(5, 0)

  // k-quarter reduction (R21). Conflict-free: slot*4096 + lane*16.
  auto st16 = [&](int slot, const float16v& v) {
    char* base = lds + slot * 4096 + lane * 16;
    *(float4v*)(base)        = (float4v){v[0],  v[1],  v[2],  v[3]};
    *(float4v*)(base + 1024) = (float4v){v[4],  v[5],  v[6],  v[7]};
    *(float4v*)(base + 2048) = (float4v){v[8],  v[9],  v[10], v[11]};
    *(float4v*)(base + 3072) = (float4v){v[12], v[13], v[14], v[15]};
  };
  auto ld16add = [&](int slot, float16v& v) {
    const char* base = lds + slot * 4096 + lane * 16;
    float4v t0 = *(const float4v*)(base);
    float4v t1 = *(const float4v*)(base + 1024);
    float4v t2 = *(const float4v*)(base + 2048);
    float4v t3 = *(const float4v*)(base + 3072);
    v[0] += t0[0]; v[1] += t0[1]; v[2]  += t0[2]; v[3]  += t0[3];
    v[4] += t1[0]; v[5] += t1[1]; v[6]  += t1[2]; v[7]  += t1[3];
    v[8] += t2[0]; v[9] += t2[1]; v[10] += t2[2]; v[11] += t2[3];
    v[12] += t3[0]; v[13] += t3[1]; v[14] += t3[2]; v[15] += t3[3];
  };

  __syncthreads();
  if (wk >= 2) {           // slots (wk-2)*2 + p2  -> 0..3
#pragma unroll
    for (int p2 = 0; p2 < 2; ++p2) st16((wk - 2) * 2 + p2, acc[0][p2]);
  }
  __syncthreads();
  if (wk < 2) {
#pragma unroll
    for (int p2 = 0; p2 < 2; ++p2) ld16add(wk * 2 + p2, acc[0][p2]);
  }
  __syncthreads();
  if (wk >= 2) {
#pragma unroll
    for (int p2 = 0; p2 < 2; ++p2) st16((wk - 2) * 2 + p2, acc[1][p2]);
  }
  __syncthreads();
  if (wk < 2) {
#pragma unroll
    for (int p2 = 0; p2 < 2; ++p2) ld16add(wk * 2 + p2, acc[1][p2]);
  }
  __syncthreads();
  if (wk == 1) {           // slots p2 (acc[0]) and 2+p2 (acc[1])
#pragma unroll
    for (int p2 = 0; p2 < 2; ++p2) { st16(p2, acc[0][p2]); st16(2 + p2, acc[1][p2]); }
  }
  __syncthreads();
  if (wk == 0) {
#pragma unroll
    for (int p2 = 0; p2 < 2; ++p2) { ld16add(p2, acc[0][p2]); ld16add(2 + p2, acc[1][p2]); }
    // Store 64n x 64pix. D layout: col=l31, row=(reg&3)+8*(reg>>2)+4*half.
#pragma unroll
    for (int mt = 0; mt < 2; ++mt) {
#pragma unroll
      for (int reg = 0; reg < 16; ++reg) {
        int n = nq * 64 + mt * 32 + (reg & 3) + 8 * (reg >> 2) + 4 * half;
        float bv = biasout[n];
#pragma unroll
        for (int p2 = 0; p2 < 2; ++p2)
          out[((b * 256 + n) * 32 + h0 + p2) * 32 + l31] = acc[mt][p2][reg] + bv;
      }
    }
  }
}

// ---------------------------------------------------------------------------
extern "C" void kernel_launch(void* const* d_in, const int* in_sizes, int n_in,
                              void* d_out, int out_size, void* d_ws, size_t ws_size,
                              hipStream_t stream) {
  const float* x    = (const float*)d_in[0];
  const float* tw1  = (const float*)d_in[1];
  const float* tw2  = (const float*)d_in[2];
  const float* bias = (const float*)d_in[3];
  float* out = (float*)d_out;

  char* ws = (char*)d_ws;
  __hip_bfloat16* xTg = (__hip_bfloat16*)ws;
  __hip_bfloat16* Wg  = (__hip_bfloat16*)(ws + XT_BYTES);
  float* biasout      = (float*)(ws + XT_BYTES + WG_BYTES);

  k_prep<<<657, 256, 0, stream>>>(x, tw1, tw2, bias, xTg, Wg, biasout);
  k_gemm<<<1024, 256, 0, stream>>>(xTg, Wg, biasout, out);
}

// Round 12
// 107.774 us; speedup vs baseline: 1.0158x; 1.0158x over previous
//
#include <hip/hip_runtime.h>
#include <hip/hip_bf16.h>

typedef __attribute__((ext_vector_type(8))) short short8;
typedef __attribute__((ext_vector_type(4))) float float4v;
typedef __attribute__((ext_vector_type(16))) float float16v;

// Workspace layout (bytes):
//   xTg  bf16 [16 b][32 g][34 h][34 w][8 c]             : 9,469,952
//   Wg   bf16 [9 s][4 pair][4 nq][8 g][64 n][8 c]       : 1,179,648
//   biasout f32 [256]                                   : 1,024
#define XT_BYTES (16*32*34*34*8*2)
#define WG_BYTES (9*4*4*8*64*8*2)

// ---------------------------------------------------------------------------
// k_prep: fused producer. (unchanged from R12)
// ---------------------------------------------------------------------------
__global__ __launch_bounds__(256) void k_prep(const float* __restrict__ x,
                                              const float* __restrict__ tw1,
                                              const float* __restrict__ tw2,
                                              const float* __restrict__ bias,
                                              __hip_bfloat16* __restrict__ xTg,
                                              __hip_bfloat16* __restrict__ Wg,
                                              float* __restrict__ biasout) {
  __shared__ __align__(16) char smem[256 * 33 * 4];   // 33792 B, both phases fit
  int blk = blockIdx.x;
  int tid = threadIdx.x;

  if (blk < 512) {   // ---------------- transpose ----------------
    float* tile = (float*)smem;
    char* xTB = (char*)xTg;
    int h = blk & 31, b = blk >> 5;
    {
      int w4 = (tid & 7) * 4, c0 = tid >> 3;
#pragma unroll
      for (int j = 0; j < 8; ++j) {
        int ci = c0 + 32 * j;
        float4 v = *(const float4*)&x[((b * 256 + ci) * 32 + h) * 32 + w4];
        *(float4*)&tile[ci * 33 + w4] = v;
      }
    }
    __syncthreads();
    {
      int g0 = tid >> 5, w = tid & 31;
#pragma unroll
      for (int gi = 0; gi < 4; ++gi) {
        int g = gi * 8 + g0;
        union { short8 s; __hip_bfloat16 hv[8]; } pk;
#pragma unroll
        for (int cc = 0; cc < 8; ++cc)
          pk.hv[cc] = __float2bfloat16(tile[(g * 8 + cc) * 33 + w]);
        *(short8*)(xTB + ((((b * 32 + g) * 34 + h + 1) * 34) + (w + 1)) * 16) = pk.s;
      }
    }
    if (h < 2) {  // h==0 -> row 0 + col 0 ; h==1 -> row 33 + col 33 (all g)
      uint4 z4 = {0u, 0u, 0u, 0u};
      int edge = h * 33;
      for (int i = tid; i < 32 * 34; i += 256) {
        int g = i / 34, w = i - g * 34;
        *(uint4*)(xTB + ((((b * 32 + g) * 34 + edge) * 34) + w) * 16) = z4;
      }
      for (int i = tid; i < 32 * 32; i += 256) {
        int g = i >> 5, hh = 1 + (i & 31);
        *(uint4*)(xTB + ((((b * 32 + g) * 34 + hh) * 34) + edge) * 16) = z4;
      }
    }
    return;
  }

  // ---------------- build_w ----------------
  int wblk = blk - 512;
  if (wblk == 144) {
    if (tid < 256) {
      float a = 0.f;
#pragma unroll
      for (int s = 0; s < 9; ++s) a += bias[s * 256 + tid];
      biasout[tid] = a * (1.f / 9.f);
    }
    return;
  }
  float* mat = (float*)smem;              // 256*17*4 = 17408 B
  float* tws = (float*)(smem + 17408);    // 2*255*4*4 = 8160 B
  int sidx = wblk >> 4;
  int colbase = (wblk & 15) * 16;

  for (int i = tid; i < 255 * 4; i += 256) {
    tws[i]           = tw1[sidx * 255 * 4 + i];
    tws[255 * 4 + i] = tw2[sidx * 255 * 4 + i];
  }
  {
    int r = tid;
#pragma unroll
    for (int c = 0; c < 16; ++c) mat[r * 17 + c] = (r == colbase + c) ? 1.f : 0.f;
  }

  int c  = tid & 15;
  int pg = tid >> 4;
  for (int ph = 0; ph < 2; ++ph) {
    for (int si = 0; si < 8; ++si) {
      int lg = ph ? si : (7 - si);
      int st = 1 << lg;
      __syncthreads();
      float x0[8], x1[8], t0[8], t1[8], t2[8], t3[8];
#pragma unroll
      for (int i = 0; i < 8; ++i) {
        int qp = pg * 8 + i;
        int li = qp & (st - 1);
        int gi = qp >> lg;
        int p0 = (gi << (lg + 1)) | li;
        int p1 = p0 + st;
        float4 tv = *(const float4*)&tws[(ph * 255 + st - 1 + li) * 4];
        t0[i] = tv.x; t1[i] = tv.y; t2[i] = tv.z; t3[i] = tv.w;
        x0[i] = mat[p0 * 17 + c];
        x1[i] = mat[p1 * 17 + c];
      }
#pragma unroll
      for (int i = 0; i < 8; ++i) {
        int qp = pg * 8 + i;
        int li = qp & (st - 1);
        int gi = qp >> lg;
        int p0 = (gi << (lg + 1)) | li;
        int p1 = p0 + st;
        mat[p0 * 17 + c] = t0[i] * x0[i] + t1[i] * x1[i];
        mat[p1 * 17 + c] = t2[i] * x0[i] + t3[i] * x1[i];
      }
    }
  }
  __syncthreads();

  for (int idx = tid; idx < 256 * 16; idx += 256) {
    int r = idx >> 4, cc = idx & 15;
    int cg = colbase + cc;
    int pr = cg >> 6, g = (cg >> 3) & 7, c8 = cg & 7;
    int nq = r >> 6, nl = r & 63;
    int o = ((((sidx * 4 + pr) * 4 + nq) * 8 + g) * 64 + nl) * 8 + c8;
    Wg[o] = __float2bfloat16(mat[r * 17 + cc] * (1.f / 9.f));
  }
}

// ---------------------------------------------------------------------------
// k_gemm R24 = R21 loop (best known; direct loads, acc[2][2], grid 1024,
// XCD swizzle) + RESTRUCTURED EPILOGUE.
// Evidence: R23's provably-6-deep pinned pipeline was NULL -> loop is
// VMEM/L1-port THROUGHPUT-bound (~2.3 MB/CU at ~64 B/cyc = the measured
// ~15 µs); only a decomposition change can beat it (future round).
// This round attacks the measured epilogue anomaly: E ~= 12-16 µs (R19
// algebra: 75.8 = 4L + E, L ~= 14.8) vs a ~3 µs arithmetic floor. Old: 6
// barriers, 3 serial LDS rounds, wk0 alone does all 64 stores, bias loads
// inline. New: 2 LDS rounds / 4 barriers; round 1 wk0+=wk2, wk1+=wk3 (same
// pairing as before); round 2 cross-exchange by mt; wk0 stores mt=0 and wk1
// stores mt=1 IN PARALLEL; bias preloaded into regs before the barriers.
// Math: only a+b <-> b+a swaps (fp add commutative) -> bit-identical.
// LDS 32 KB (8 slots), 4 blocks/CU retained (128 KB/CU <= 160).
// ---------------------------------------------------------------------------
__global__ __launch_bounds__(256, 4) void k_gemm(const __hip_bfloat16* __restrict__ xTg,
                                                 const __hip_bfloat16* __restrict__ Wg,
                                                 const float* __restrict__ biasout,
                                                 float* __restrict__ out) {
  __shared__ __align__(64) char lds[32768];
  const char* WgB = (const char*)Wg;
  const char* xTB = (const char*)xTg;

  // XCD swizzle: xcd = blk&7 owns b in {2*xcd, 2*xcd+1}. Grid 1024.
  int blk  = blockIdx.x;
  int rest = blk >> 3;              // 0..127
  int b    = 2 * (blk & 7) + (rest >> 6);
  int r2   = rest & 63;
  int nq   = r2 & 3;
  int pt   = r2 >> 2;               // 0..15
  int h0   = pt * 2;                // output rows h0, h0+1

  int tid  = threadIdx.x;
  int lane = tid & 63;
  int wk   = tid >> 6;              // wave = k-quarter 0..3
  int half = lane >> 5;
  int l31  = lane & 31;

  float16v acc[2][2];               // [mt][p2] -- 64 regs
#pragma unroll
  for (int mt = 0; mt < 2; ++mt)
#pragma unroll
    for (int p2 = 0; p2 < 2; ++p2)
#pragma unroll
      for (int e = 0; e < 16; ++e) acc[mt][p2][e] = 0.f;

  // A: within a slab, octet (2wk+half), rows mt*32+l31 (+512 B for mt=1).
  int aoff = ((2 * wk + half) * 64 + l31) * 16;
  // B: octet (2wk+half) of chan-pair p, padded row h0, col l31.
  int bbase = ((((b * 32 + 2 * wk + half) * 34 + h0) * 34) + l31) * 16;

#pragma unroll 2
  for (int p = 0; p < 4; ++p) {
    const char* Bp = xTB + bbase + p * (8 * 34 * 34) * 16;
    const char* Ap = WgB + (p * 4 + nq) * 8192;
#pragma unroll
    for (int si = 0; si < 3; ++si) {
#pragma unroll
      for (int sj = 0; sj < 3; ++sj) {
        const char* Aslab = Ap + (si * 3 + sj) * (16 * 8192);
        short8 a0 = *(const short8*)(Aslab + aoff);
        short8 a1 = *(const short8*)(Aslab + aoff + 32 * 16);
        const char* Bq = Bp + (si * 34 + sj) * 16;
        short8 b0 = *(const short8*)(Bq);
        short8 b1 = *(const short8*)(Bq + 34 * 16);
        acc[0][0] = __builtin_amdgcn_mfma_f32_32x32x16_bf16(a0, b0, acc[0][0], 0, 0, 0);
        acc[0][1] = __builtin_amdgcn_mfma_f32_32x32x16_bf16(a0, b1, acc[0][1], 0, 0, 0);
        acc[1][0] = __builtin_amdgcn_mfma_f32_32x32x16_bf16(a1, b0, acc[1][0], 0, 0, 0);
        acc[1][1] = __builtin_amdgcn_mfma_f32_32x32x16_bf16(a1, b1, acc[1][1], 0, 0, 0);
      }
    }
  }

  // Bias preload (latency hidden under the reduction barriers).
  // wk0 stores mt=0 (n base nq*64), wk1 stores mt=1 (n base nq*64+32).
  float bv[16];
  if (wk < 2) {
#pragma unroll
    for (int reg = 0; reg < 16; ++reg)
      bv[reg] = biasout[nq * 64 + wk * 32 + (reg & 3) + 8 * (reg >> 2) + 4 * half];
  }

  // LDS helpers: slot*4096 + lane*16, 4 chunks @ +1024 (conflict-free b128).
  auto st16 = [&](int slot, const float16v& v) {
    char* base = lds + slot * 4096 + lane * 16;
    *(float4v*)(base)        = (float4v){v[0],  v[1],  v[2],  v[3]};
    *(float4v*)(base + 1024) = (float4v){v[4],  v[5],  v[6],  v[7]};
    *(float4v*)(base + 2048) = (float4v){v[8],  v[9],  v[10], v[11]};
    *(float4v*)(base + 3072) = (float4v){v[12], v[13], v[14], v[15]};
  };
  auto ld16add = [&](int slot, float16v& v) {
    const char* base = lds + slot * 4096 + lane * 16;
    float4v t0 = *(const float4v*)(base);
    float4v t1 = *(const float4v*)(base + 1024);
    float4v t2 = *(const float4v*)(base + 2048);
    float4v t3 = *(const float4v*)(base + 3072);
    v[0] += t0[0]; v[1] += t0[1]; v[2]  += t0[2]; v[3]  += t0[3];
    v[4] += t1[0]; v[5] += t1[1]; v[6]  += t1[2]; v[7]  += t1[3];
    v[8] += t2[0]; v[9] += t2[1]; v[10] += t2[2]; v[11] += t2[3];
    v[12] += t3[0]; v[13] += t3[1]; v[14] += t3[2]; v[15] += t3[3];
  };

  // Round 1: wk2 -> slots 0..3, wk3 -> slots 4..7; wk0 += wk2, wk1 += wk3.
  __syncthreads();
  if (wk == 2) { st16(0, acc[0][0]); st16(1, acc[0][1]); st16(2, acc[1][0]); st16(3, acc[1][1]); }
  if (wk == 3) { st16(4, acc[0][0]); st16(5, acc[0][1]); st16(6, acc[1][0]); st16(7, acc[1][1]); }
  __syncthreads();
  if (wk == 0) { ld16add(0, acc[0][0]); ld16add(1, acc[0][1]); ld16add(2, acc[1][0]); ld16add(3, acc[1][1]); }
  if (wk == 1) { ld16add(4, acc[0][0]); ld16add(5, acc[0][1]); ld16add(6, acc[1][0]); ld16add(7, acc[1][1]); }
  __syncthreads();
  // Round 2: cross-exchange by mt. wk1 gives its mt0 partial to wk0 (slots
  // 0,1); wk0 gives its mt1 partial to wk1 (slots 4,5).
  if (wk == 1) { st16(0, acc[0][0]); st16(1, acc[0][1]); }
  if (wk == 0) { st16(4, acc[1][0]); st16(5, acc[1][1]); }
  __syncthreads();
  // Final: wk0 stores mt=0, wk1 stores mt=1, in parallel.
  // D layout: col=l31, row=(reg&3)+8*(reg>>2)+4*half.
  if (wk == 0) {
    ld16add(0, acc[0][0]); ld16add(1, acc[0][1]);   // (w0+w2)+(w1+w3), mt0
#pragma unroll
    for (int reg = 0; reg < 16; ++reg) {
      int n = nq * 64 + (reg & 3) + 8 * (reg >> 2) + 4 * half;
      float* o0 = &out[((b * 256 + n) * 32 + h0) * 32 + l31];
      o0[0]  = acc[0][0][reg] + bv[reg];
      o0[32] = acc[0][1][reg] + bv[reg];
    }
  }
  if (wk == 1) {
    ld16add(4, acc[1][0]); ld16add(5, acc[1][1]);   // (w1+w3)+(w0+w2), mt1
#pragma unroll
    for (int reg = 0; reg < 16; ++reg) {
      int n = nq * 64 + 32 + (reg & 3) + 8 * (reg >> 2) + 4 * half;
      float* o0 = &out[((b * 256 + n) * 32 + h0) * 32 + l31];
      o0[0]  = acc[1][0][reg] + bv[reg];
      o0[32] = acc[1][1][reg] + bv[reg];
    }
  }
}

// ---------------------------------------------------------------------------
extern "C" void kernel_launch(void* const* d_in, const int* in_sizes, int n_in,
                              void* d_out, int out_size, void* d_ws, size_t ws_size,
                              hipStream_t stream) {
  const float* x    = (const float*)d_in[0];
  const float* tw1  = (const float*)d_in[1];
  const float* tw2  = (const float*)d_in[2];
  const float* bias = (const float*)d_in[3];
  float* out = (float*)d_out;

  char* ws = (char*)d_ws;
  __hip_bfloat16* xTg = (__hip_bfloat16*)ws;
  __hip_bfloat16* Wg  = (__hip_bfloat16*)(ws + XT_BYTES);
  float* biasout      = (float*)(ws + XT_BYTES + WG_BYTES);

  k_prep<<<657, 256, 0, stream>>>(x, tw1, tw2, bias, xTg, Wg, biasout);
  k_gemm<<<1024, 256, 0, stream>>>(xTg, Wg, biasout, out);
}